// Round 8
// baseline (9.672 us; speedup 1.0000x reference)
//
#include <hip/hip_runtime.h>
#include <math.h>

#define N_MAX 4096
#define NTHR  256
#define EPT   16                // elements per thread
#define CS    32
#define NCHUNK (N_MAX / CS)     // 128
#define NWAVE (NTHR / 64)       // 4

// Reduce 4 float sums across the block (nthr threads). scr >= 64 floats.
template <int TN>
__device__ inline void block_reduce4(float& x, float& y, float& z, float& w,
                                     volatile float* scr, int tid) {
#pragma unroll
  for (int o = 32; o > 0; o >>= 1) {
    x += __shfl_down(x, o, 64);
    y += __shfl_down(y, o, 64);
    z += __shfl_down(z, o, 64);
    w += __shfl_down(w, o, 64);
  }
  const int wv = tid >> 6, ln = tid & 63;
  __syncthreads();
  if (ln == 0) { scr[wv] = x; scr[16 + wv] = y; scr[32 + wv] = z; scr[48 + wv] = w; }
  __syncthreads();
  if (tid == 0) {
    float sx = 0.f, sy = 0.f, sz = 0.f, sw = 0.f;
    for (int k = 0; k < TN / 64; ++k) {
      sx += scr[k]; sy += scr[16 + k]; sz += scr[32 + k]; sw += scr[48 + k];
    }
    scr[0] = sx; scr[16] = sy; scr[32] = sz; scr[48] = sw;
  }
  __syncthreads();
  x = scr[0]; y = scr[16]; z = scr[32]; w = scr[48];
}

// ---- Fast kernel: tiny LDS; fallback arrays live in global ws ----
__global__ __launch_bounds__(NTHR, 1)
void spearman_fast(const float* __restrict__ pred,
                   const float* __restrict__ target,
                   float* __restrict__ out,
                   float* __restrict__ g_val, float* __restrict__ g_tp,
                   float* __restrict__ g_q, int* __restrict__ g_idx,
                   int* __restrict__ gst_cnt, int* __restrict__ gst_start,
                   double* __restrict__ gst_sum, int n) {
  __shared__ float s_part[6 * NWAVE];
  __shared__ unsigned int s_mlo[NWAVE], s_mhi[NWAVE];
  __shared__ int   s_flag[NWAVE];
  __shared__ float s_red[64];
  __shared__ float s_sums[6];
  __shared__ int   s_nb[NCHUNK];
  __shared__ int   s_sp;

  const int tid = threadIdx.x;
  const int wv = tid >> 6, ln = tid & 63;

  // ---- Load EPT contiguous elements per thread into registers ----
  float p[EPT], t[EPT];
  const int base = tid * EPT;
  int cntv = 0;
  if (base + EPT - 1 < n) {
#pragma unroll
    for (int q = 0; q < EPT / 4; ++q) {
      const float4 pv = *(const float4*)&pred[base + q * 4];
      const float4 tv = *(const float4*)&target[base + q * 4];
      p[q*4+0]=pv.x; p[q*4+1]=pv.y; p[q*4+2]=pv.z; p[q*4+3]=pv.w;
      t[q*4+0]=tv.x; t[q*4+1]=tv.y; t[q*4+2]=tv.z; t[q*4+3]=tv.w;
    }
    cntv = EPT;
  } else {
#pragma unroll
    for (int u = 0; u < EPT; ++u) {
      const int i = base + u;
      if (i < n) { p[u] = pred[i]; t[u] = target[i]; cntv = u + 1; }
      else       { p[u] = 0.f; t[u] = 0.f; }
    }
  }
  const float anchor = pred[0];   // uniform scalar load, overlaps vector loads

  // ---- One pass: partial sums + register emptiness mask ----
  float s0=0.f,s1=0.f,s2=0.f,s3=0.f,s4=0.f,s5=0.f;
  unsigned long long m = 0ull;
  int oow = 0;
#pragma unroll
  for (int u = 0; u < EPT; ++u) {
    if (u < cntv) {
      s0 += p[u]; s1 += p[u]*p[u];
      s2 += t[u]; s3 += t[u]*t[u];
      s4 += p[u]*t[u];
      const float d = p[u] - t[u];
      s5 += d*d;
      const int b = (int)floorf((p[u] - anchor) * 4.0f) + 32;
      if (b < 0 || b > 63) oow = 1;
      else m |= (1ull << b);
    }
  }

  // ---- Wave-level reduce: 6 sums (+), mask (|), flag (|) ----
  unsigned int mlo = (unsigned int)m, mhi = (unsigned int)(m >> 32);
#pragma unroll
  for (int o = 32; o > 0; o >>= 1) {
    s0 += __shfl_down(s0, o, 64); s1 += __shfl_down(s1, o, 64);
    s2 += __shfl_down(s2, o, 64); s3 += __shfl_down(s3, o, 64);
    s4 += __shfl_down(s4, o, 64); s5 += __shfl_down(s5, o, 64);
    mlo |= (unsigned int)__shfl_down((int)mlo, o, 64);
    mhi |= (unsigned int)__shfl_down((int)mhi, o, 64);
    oow |= __shfl_down(oow, o, 64);
  }
  if (ln == 0) {
    s_part[0*NWAVE+wv]=s0; s_part[1*NWAVE+wv]=s1; s_part[2*NWAVE+wv]=s2;
    s_part[3*NWAVE+wv]=s3; s_part[4*NWAVE+wv]=s4; s_part[5*NWAVE+wv]=s5;
    s_mlo[wv] = mlo; s_mhi[wv] = mhi; s_flag[wv] = oow;
  }
  __syncthreads();                 // the ONLY barrier on the fast path

  // ---- All threads derive `safe` identically from the 4 wave masks ----
  unsigned long long nonempty = 0ull;
  int flag = 0;
#pragma unroll
  for (int k = 0; k < NWAVE; ++k) {
    nonempty |= ((unsigned long long)s_mhi[k] << 32) | s_mlo[k];
    flag |= s_flag[k];
  }
  int safe = (flag == 0) && (nonempty != 0ull);
  if (safe) {
    const int minb = __ffsll((long long)nonempty) - 1;
    const int maxb = 63 - __clzll((long long)nonempty);
    const int span = maxb - minb;
    const unsigned long long R =
        (span >= 63) ? ~0ull : (((1ull << (span + 1)) - 1ull) << minb);
    const unsigned long long em = (~nonempty) & R;
    if (em & (em >> 1) & (em >> 2)) safe = 0;  // 3 consecutive empty bins
  }

  if (safe) {
    if (tid == 0) {
      // All sorted gaps < 1 => z = s - [n..1] strictly increasing => PAV
      // pools totally => loss = MSE - 0.1 * pearson(pred, target).
      float S[6];
#pragma unroll
      for (int q = 0; q < 6; ++q) {
        float acc = s_part[q*NWAVE];
#pragma unroll
        for (int k = 1; k < NWAVE; ++k) acc += s_part[q*NWAVE+k];
        S[q] = acc;
      }
      const double nn = (double)n;
      const double Sp = S[0], Spp = S[1], St = S[2], Stt = S[3],
                   Spt = S[4], Sdd = S[5];
      const double cov = Spt - Sp * St / nn;
      const double vp  = Spp - Sp * Sp / nn;
      const double vt  = Stt - St * St / nn;
      out[0] = (float)(-0.1 * cov / sqrt(vp * vt) + Sdd / nn);
    }
    return;   // uniform decision across the block
  }

  // ====== Fallback: exact bitonic + PAV on GLOBAL scratch (rare path) =====
  if (tid == 0) {
#pragma unroll
    for (int q = 0; q < 6; ++q) {
      float acc = s_part[q*NWAVE];
#pragma unroll
      for (int k = 1; k < NWAVE; ++k) acc += s_part[q*NWAVE+k];
      s_sums[q] = acc;
    }
  }
#pragma unroll
  for (int u = 0; u < EPT; ++u) {
    const int i = base + u;
    if (i < n) { g_val[i] = p[u]; g_tp[i] = t[u]; }
    else       { g_val[i] = -3.0e38f; g_tp[i] = 0.f; }
    g_idx[i] = i;
  }
  __syncthreads();

  for (int k = 2; k <= N_MAX; k <<= 1) {
    for (int j = k >> 1; j >= 1; j >>= 1) {
#pragma unroll 2
      for (int tq = tid; tq < N_MAX / 2; tq += NTHR) {
        const int l = tq & (j - 1);
        const int i = ((tq ^ l) << 1) | l;
        const int pp = i | j;
        const bool up = ((i & k) == 0);
        const float a = g_val[i], b = g_val[pp];
        if ((a < b) == up) {
          g_val[i] = b; g_val[pp] = a;
          const int ia = g_idx[i]; g_idx[i] = g_idx[pp]; g_idx[pp] = ia;
        }
      }
      __syncthreads();
    }
  }

  if (tid < NCHUNK) {
    const int cbase = tid * CS;
    const int lim  = (n - cbase < CS) ? (n - cbase) : CS;
    int sp = 0; double tsum = 0.0; int tcnt = 0, tstart = 0;
    for (int k = 0; k < lim; ++k) {
      const int i = cbase + k;
      double cs_ = (double)g_val[i] - (double)(n - i);
      int cc = 1, cst = i;
      while (sp > 0 && tsum * (double)cc <= cs_ * (double)tcnt) {
        cs_ += tsum; cc += tcnt; cst = tstart; sp--;
        if (sp > 0) {
          tsum = gst_sum[cbase + sp - 1]; tcnt = gst_cnt[cbase + sp - 1];
          tstart = gst_start[cbase + sp - 1];
        }
      }
      if (sp > 0) {
        gst_sum[cbase + sp - 1] = tsum; gst_cnt[cbase + sp - 1] = tcnt;
        gst_start[cbase + sp - 1] = tstart;
      }
      tsum = cs_; tcnt = cc; tstart = cst; sp++;
    }
    if (lim > 0) {
      gst_sum[cbase + sp - 1] = tsum; gst_cnt[cbase + sp - 1] = tcnt;
      gst_start[cbase + sp - 1] = tstart; s_nb[tid] = sp;
    } else s_nb[tid] = 0;
  }
  __syncthreads();

  if (tid == 0) {
    int gp = 0; double tsum = 0.0; int tcnt = 0, tstart = 0;
    for (int c = 0; c < NCHUNK; ++c) {
      const int nb = s_nb[c], rb = c * CS;
      for (int k = 0; k < nb; ++k) {
        double cs_ = gst_sum[rb + k];
        int cc = gst_cnt[rb + k], cst = gst_start[rb + k];
        while (gp > 0 && tsum * (double)cc <= cs_ * (double)tcnt) {
          cs_ += tsum; cc += tcnt; cst = tstart; gp--;
          if (gp > 0) {
            tsum = gst_sum[gp - 1]; tcnt = gst_cnt[gp - 1]; tstart = gst_start[gp - 1];
          }
        }
        if (gp > 0) {
          gst_sum[gp - 1] = tsum; gst_cnt[gp - 1] = tcnt; gst_start[gp - 1] = tstart;
        }
        tsum = cs_; tcnt = cc; tstart = cst; gp++;
      }
    }
    if (gp > 0) { gst_sum[gp - 1] = tsum; gst_cnt[gp - 1] = tcnt; gst_start[gp - 1] = tstart; }
    s_sp = gp;
    const double Cd = 0.5 * (double)(n + 1);
    for (int b = 0; b < gp; ++b)
      g_q[b] = (float)(gst_sum[b] / (double)gst_cnt[b] + Cd);
  }
  __syncthreads();

  const int sp = s_sp;
  float b0 = 0.f, b1 = 0.f, b2 = 0.f, b3 = 0.f;
  for (int i = tid; i < n; i += NTHR) {
    int lo = 0, hi = sp - 1;
    while (lo < hi) {
      const int mid = (lo + hi + 1) >> 1;
      if (gst_start[mid] <= i) lo = mid; else hi = mid - 1;
    }
    const float rc = g_val[i] - g_q[lo];
    const float tt = g_tp[g_idx[i]];
    b0 += rc; b1 += rc * rc; b2 += rc * tt;
  }
  block_reduce4<NTHR>(b0, b1, b2, b3, s_red, tid);

  if (tid == 0) {
    const double nn = (double)n;
    const double St = s_sums[2], Stt = s_sums[3], Sdd = s_sums[5];
    const double cov = (double)b2 - (double)b0 * St / nn;
    const double vr  = (double)b1 - (double)b0 * (double)b0 / nn;
    const double vt  = Stt - St * St / nn;
    out[0] = (float)(-0.1 * cov / sqrt(vr * vt) + Sdd / nn);
  }
}

// ---- R7-validated full-LDS kernel (used only if ws is too small) ----
__global__ __launch_bounds__(NTHR, 1)
void spearman_mono(const float* __restrict__ pred,
                   const float* __restrict__ target,
                   float* __restrict__ out, int n) {
  __shared__ float  s_val[N_MAX];
  __shared__ int    s_idx[N_MAX];
  __shared__ float  s_tp[N_MAX];
  __shared__ float  s_q[N_MAX];
  __shared__ double st_sum[N_MAX];
  __shared__ int    st_cnt[N_MAX];
  __shared__ int    st_start[N_MAX];
  __shared__ int    s_nb[NCHUNK];
  __shared__ int    s_sp;
  __shared__ float  s_red[64];
  __shared__ float  s_part[6 * NWAVE];
  __shared__ float  s_sums[6];
  __shared__ int    s_bins[64];
  __shared__ int    s_flag;

  const int tid = threadIdx.x;
  const int wv = tid >> 6, ln = tid & 63;

  float p[EPT], t[EPT];
  const int base = tid * EPT;
  int cntv = 0;
  if (base + EPT - 1 < n) {
#pragma unroll
    for (int q = 0; q < EPT / 4; ++q) {
      const float4 pv = *(const float4*)&pred[base + q * 4];
      const float4 tv = *(const float4*)&target[base + q * 4];
      p[q*4+0]=pv.x; p[q*4+1]=pv.y; p[q*4+2]=pv.z; p[q*4+3]=pv.w;
      t[q*4+0]=tv.x; t[q*4+1]=tv.y; t[q*4+2]=tv.z; t[q*4+3]=tv.w;
    }
    cntv = EPT;
  } else {
#pragma unroll
    for (int u = 0; u < EPT; ++u) {
      const int i = base + u;
      if (i < n) { p[u] = pred[i]; t[u] = target[i]; cntv = u + 1; }
      else       { p[u] = 0.f; t[u] = 0.f; }
    }
  }
  const float anchor = pred[0];

  if (tid < 64) s_bins[tid] = 0;
  if (tid == 0) s_flag = 0;
  __syncthreads();

  float s0=0.f,s1=0.f,s2=0.f,s3=0.f,s4=0.f,s5=0.f;
  int oow = 0;
#pragma unroll
  for (int u = 0; u < EPT; ++u) {
    if (u < cntv) {
      s0 += p[u]; s1 += p[u]*p[u];
      s2 += t[u]; s3 += t[u]*t[u];
      s4 += p[u]*t[u];
      const float d = p[u] - t[u];
      s5 += d*d;
      const int b = (int)floorf((p[u] - anchor) * 4.0f) + 32;
      if (b < 0 || b > 63) oow = 1;
      else s_bins[b] = 1;
    }
  }
  if (oow) s_flag = 1;

#pragma unroll
  for (int o = 32; o > 0; o >>= 1) {
    s0 += __shfl_down(s0, o, 64); s1 += __shfl_down(s1, o, 64);
    s2 += __shfl_down(s2, o, 64); s3 += __shfl_down(s3, o, 64);
    s4 += __shfl_down(s4, o, 64); s5 += __shfl_down(s5, o, 64);
  }
  if (ln == 0) {
    s_part[0*NWAVE+wv]=s0; s_part[1*NWAVE+wv]=s1; s_part[2*NWAVE+wv]=s2;
    s_part[3*NWAVE+wv]=s3; s_part[4*NWAVE+wv]=s4; s_part[5*NWAVE+wv]=s5;
  }
  __syncthreads();

  const unsigned long long nonempty = __ballot(s_bins[ln] != 0);
  int safe = (s_flag == 0) && (nonempty != 0ull);
  if (safe) {
    const int minb = __ffsll((long long)nonempty) - 1;
    const int maxb = 63 - __clzll((long long)nonempty);
    const int span = maxb - minb;
    const unsigned long long R =
        (span >= 63) ? ~0ull : (((1ull << (span + 1)) - 1ull) << minb);
    const unsigned long long em = (~nonempty) & R;
    if (em & (em >> 1) & (em >> 2)) safe = 0;
  }

  if (safe) {
    if (tid == 0) {
      float S[6];
#pragma unroll
      for (int q = 0; q < 6; ++q)
        S[q] = s_part[q*NWAVE+0] + s_part[q*NWAVE+1] + s_part[q*NWAVE+2] + s_part[q*NWAVE+3];
      const double nn = (double)n;
      const double cov = (double)S[4] - (double)S[0] * (double)S[2] / nn;
      const double vp  = (double)S[1] - (double)S[0] * (double)S[0] / nn;
      const double vt  = (double)S[3] - (double)S[2] * (double)S[2] / nn;
      out[0] = (float)(-0.1 * cov / sqrt(vp * vt) + (double)S[5] / nn);
    }
    return;
  }

  if (tid == 0) {
#pragma unroll
    for (int q = 0; q < 6; ++q)
      s_sums[q] = s_part[q*NWAVE+0] + s_part[q*NWAVE+1] + s_part[q*NWAVE+2] + s_part[q*NWAVE+3];
  }
#pragma unroll
  for (int u = 0; u < EPT; ++u) {
    const int i = base + u;
    if (i < n) { s_val[i] = p[u]; s_tp[i] = t[u]; }
    else       { s_val[i] = -3.0e38f; s_tp[i] = 0.f; }
    s_idx[i] = i;
  }
  __syncthreads();

  for (int k = 2; k <= N_MAX; k <<= 1) {
    for (int j = k >> 1; j >= 1; j >>= 1) {
#pragma unroll 2
      for (int tq = tid; tq < N_MAX / 2; tq += NTHR) {
        const int l = tq & (j - 1);
        const int i = ((tq ^ l) << 1) | l;
        const int pp = i | j;
        const bool up = ((i & k) == 0);
        const float a = s_val[i], b = s_val[pp];
        if ((a < b) == up) {
          s_val[i] = b; s_val[pp] = a;
          const int ia = s_idx[i]; s_idx[i] = s_idx[pp]; s_idx[pp] = ia;
        }
      }
      __syncthreads();
    }
  }

  if (tid < NCHUNK) {
    const int cbase = tid * CS;
    const int lim  = (n - cbase < CS) ? (n - cbase) : CS;
    int sp = 0; double tsum = 0.0; int tcnt = 0, tstart = 0;
    for (int k = 0; k < lim; ++k) {
      const int i = cbase + k;
      double cs_ = (double)s_val[i] - (double)(n - i);
      int cc = 1, cst = i;
      while (sp > 0 && tsum * (double)cc <= cs_ * (double)tcnt) {
        cs_ += tsum; cc += tcnt; cst = tstart; sp--;
        if (sp > 0) {
          tsum = st_sum[cbase + sp - 1]; tcnt = st_cnt[cbase + sp - 1];
          tstart = st_start[cbase + sp - 1];
        }
      }
      if (sp > 0) {
        st_sum[cbase + sp - 1] = tsum; st_cnt[cbase + sp - 1] = tcnt;
        st_start[cbase + sp - 1] = tstart;
      }
      tsum = cs_; tcnt = cc; tstart = cst; sp++;
    }
    if (lim > 0) {
      st_sum[cbase + sp - 1] = tsum; st_cnt[cbase + sp - 1] = tcnt;
      st_start[cbase + sp - 1] = tstart; s_nb[tid] = sp;
    } else s_nb[tid] = 0;
  }
  __syncthreads();

  if (tid == 0) {
    int gp = 0; double tsum = 0.0; int tcnt = 0, tstart = 0;
    for (int c = 0; c < NCHUNK; ++c) {
      const int nb = s_nb[c], rb = c * CS;
      for (int k = 0; k < nb; ++k) {
        double cs_ = st_sum[rb + k];
        int cc = st_cnt[rb + k], cst = st_start[rb + k];
        while (gp > 0 && tsum * (double)cc <= cs_ * (double)tcnt) {
          cs_ += tsum; cc += tcnt; cst = tstart; gp--;
          if (gp > 0) {
            tsum = st_sum[gp - 1]; tcnt = st_cnt[gp - 1]; tstart = st_start[gp - 1];
          }
        }
        if (gp > 0) {
          st_sum[gp - 1] = tsum; st_cnt[gp - 1] = tcnt; st_start[gp - 1] = tstart;
        }
        tsum = cs_; tcnt = cc; tstart = cst; gp++;
      }
    }
    if (gp > 0) { st_sum[gp - 1] = tsum; st_cnt[gp - 1] = tcnt; st_start[gp - 1] = tstart; }
    s_sp = gp;
    const double Cd = 0.5 * (double)(n + 1);
    for (int b = 0; b < gp; ++b)
      s_q[b] = (float)(st_sum[b] / (double)st_cnt[b] + Cd);
  }
  __syncthreads();

  const int sp = s_sp;
  float b0 = 0.f, b1 = 0.f, b2 = 0.f, b3 = 0.f;
  for (int i = tid; i < n; i += NTHR) {
    int lo = 0, hi = sp - 1;
    while (lo < hi) {
      const int mid = (lo + hi + 1) >> 1;
      if (st_start[mid] <= i) lo = mid; else hi = mid - 1;
    }
    const float rc = s_val[i] - s_q[lo];
    const float tt = s_tp[s_idx[i]];
    b0 += rc; b1 += rc * rc; b2 += rc * tt;
  }
  block_reduce4<NTHR>(b0, b1, b2, b3, s_red, tid);

  if (tid == 0) {
    const double nn = (double)n;
    const double St = s_sums[2], Stt = s_sums[3], Sdd = s_sums[5];
    const double cov = (double)b2 - (double)b0 * St / nn;
    const double vr  = (double)b1 - (double)b0 * (double)b0 / nn;
    const double vt  = Stt - St * St / nn;
    out[0] = (float)(-0.1 * cov / sqrt(vr * vt) + Sdd / nn);
  }
}

extern "C" void kernel_launch(void* const* d_in, const int* in_sizes, int n_in,
                              void* d_out, int out_size, void* d_ws, size_t ws_size,
                              hipStream_t stream) {
  const float* pred   = (const float*)d_in[0];
  const float* target = (const float*)d_in[1];
  float* out = (float*)d_out;
  const int n = in_sizes[0];

  // ws layout (bytes): g_val 16K | g_tp 16K | g_q 16K | g_idx 16K |
  //                    gst_cnt 16K | gst_start 16K | gst_sum 32K  = 128K
  const size_t need = (size_t)N_MAX * 32;
  if (ws_size >= need) {
    char* W = (char*)d_ws;
    spearman_fast<<<1, NTHR, 0, stream>>>(
        pred, target, out,
        (float*)W, (float*)(W + 16384), (float*)(W + 32768), (int*)(W + 49152),
        (int*)(W + 65536), (int*)(W + 81920), (double*)(W + 98304), n);
  } else {
    spearman_mono<<<1, NTHR, 0, stream>>>(pred, target, out, n);
  }
}